// Round 4
// baseline (331.209 us; speedup 1.0000x reference)
//
#include <hip/hip_runtime.h>
#include <hip/hip_bf16.h>
#include <stdint.h>

// ---------------------------------------------------------------------------
// HeadAttention: Q=xq*W^T+b, K=xk*W^T+b, V=xv*W^T+b (same W,b),
// O = softmax(causal(Q K^T / 32)) V.    B=4, S=2048, E=1024, fp32 in/out.
// R9: R5 skeleton (256thr/4wave/128x128/BK=32/32KB LDS, same grids+mappings
// +epilogues) with ONLY the K-loop schedule changed, all three GEMMs:
//   - true double-buffer (buf parity = tile parity)
//   - stage tile t+1 BEFORE computing tile t; wait with counted vmcnt(4)
//     (exactly t+1's 4 per-thread loads in flight; vmcnt(0) only on last)
//   - raw s_barrier (no compiler vmcnt(0) drain)
//   - T2 chunk swizzle (stage src + read): chunk ^= (r&3)^((r>>2)&3)
//     -> 8-way bank conflict (6.29M cyc measured) becomes free 2-way
//   - T5 setprio(1) around the 16-MFMA cluster
// Race-freedom: reads of buf[p] complete before iter-p's closing barrier
// (MFMA consumes them); buf[p] re-staged only after that barrier (WAR ok);
// reads of tile t start after vmcnt(4)+barrier where the only younger VMEM
// is tile t+1's exactly-4 loads (RAW ok, uniform 4 loads/thread/iter).
// ---------------------------------------------------------------------------

typedef __attribute__((ext_vector_type(8))) short bf16x8;
typedef __attribute__((ext_vector_type(4))) float floatx4;

#define DEVI static __device__ __forceinline__

static constexpr int S_ = 2048;
static constexpr int E_ = 1024;
static constexpr int BATCH = 4;
static constexpr int N4X = 8192 * 1024 / 4;  // float4 count per X input

DEVI unsigned short f2b(float f) {
  union { float f; unsigned u; } v; v.f = f;
  return (unsigned short)((v.u + 0x7FFFu + ((v.u >> 16) & 1u)) >> 16); // RNE
}

DEVI void async_load16(const void* g, void* l) {
  __builtin_amdgcn_global_load_lds(
      (__attribute__((address_space(1))) void*)(void*)(g),
      (__attribute__((address_space(3))) void*)(l),
      16, 0, 0);
}

// Latin-square chunk swizzle for 128x32 tiles (4 x 16B chunks per row):
// within any 16 consecutive rows at fixed logical chunk, all 4 slots cycle
// twice per bank-phase -> 2-way (free) instead of 8-way.
DEVI int swz(int row) { return (row & 3) ^ ((row >> 2) & 3); }

// stage a 128x32 bf16 tile (async DMA, 2 x 16B per thread), row stride `ld`.
// LDS dest linear (global_load_lds requirement); source chunk permuted so
// LDS slot s of row r holds logical chunk s ^ swz(r).
DEVI void stage32(const unsigned short* __restrict__ src, unsigned short* ls,
                  int ld, int tid) {
#pragma unroll
  for (int j = 0; j < 2; ++j) {
    int t = tid + j * 256, row = t >> 2, slot = t & 3;
    async_load16(src + (size_t)row * ld + ((slot ^ swz(row)) << 3), ls + t * 8);
  }
}

// read logical (row r, chunk g [8 bf16]) from a swizzled 128x32 tile
DEVI bf16x8 ldf(const unsigned short* ls, int r, int g) {
  return *(const bf16x8*)(ls + r * 32 + ((g ^ swz(r)) << 3));
}

// ---------------------------------------------------------------------------
// Pipelined K-loop shared by all three GEMMs.  Per tile: 8 ds_read_b128 +
// 16 MFMA per wave (m97 inner shape), compiler-scheduled lgkmcnt interleave.
// ---------------------------------------------------------------------------
DEVI void kloop(const unsigned short* __restrict__ A, int lda,
                const unsigned short* __restrict__ Bt, int ldb, int NT,
                unsigned short* lsA0, unsigned short* lsA1,
                unsigned short* lsB0, unsigned short* lsB1, int tid, int m0,
                int n0, int lrow, int g, floatx4 (&acc)[4][4]) {
  stage32(A, lsA0, lda, tid);
  stage32(Bt, lsB0, ldb, tid);
  for (int t = 0; t < NT; ++t) {
    const int cur = t & 1;
    unsigned short* la = cur ? lsA1 : lsA0;
    unsigned short* lb = cur ? lsB1 : lsB0;
    if (t + 1 < NT) {
      // prefetch tile t+1 into the other buffer (its reads ended last iter)
      stage32(A + (t + 1) * 32, cur ? lsA0 : lsA1, lda, tid);
      stage32(Bt + (t + 1) * 32, cur ? lsB0 : lsB1, ldb, tid);
      asm volatile("s_waitcnt vmcnt(4)" ::: "memory");  // tile t landed
    } else {
      asm volatile("s_waitcnt vmcnt(0)" ::: "memory");
    }
    asm volatile("s_barrier" ::: "memory");
    bf16x8 af[4], bfr[4];
#pragma unroll
    for (int i = 0; i < 4; ++i) af[i] = ldf(la, m0 + i * 16 + lrow, g);
#pragma unroll
    for (int i = 0; i < 4; ++i) bfr[i] = ldf(lb, n0 + i * 16 + lrow, g);
    __builtin_amdgcn_s_setprio(1);
#pragma unroll
    for (int mi = 0; mi < 4; ++mi)
#pragma unroll
      for (int ni = 0; ni < 4; ++ni)
        acc[mi][ni] = __builtin_amdgcn_mfma_f32_16x16x32_bf16(
            af[mi], bfr[ni], acc[mi][ni], 0, 0, 0);
    __builtin_amdgcn_s_setprio(0);
    if (t + 1 < NT) asm volatile("s_barrier" ::: "memory");  // reads done
  }
}

// fp32 -> bf16 convert: xq|xk|xv -> Xb, Wq -> Wb, one dispatch
__global__ void cvt_all(const float* __restrict__ xq,
                        const float* __restrict__ xk,
                        const float* __restrict__ xv,
                        const float* __restrict__ Wq,
                        unsigned short* __restrict__ Xb,
                        unsigned short* __restrict__ Wb) {
  int i = blockIdx.x * blockDim.x + threadIdx.x;
  const float4* src;
  ushort4* dst;
  if (i < 3 * N4X) {
    int seg = i / N4X, off = i - seg * N4X;
    const float* s = (seg == 0) ? xq : (seg == 1) ? xk : xv;
    src = (const float4*)s + off;
    dst = (ushort4*)(Xb + (size_t)seg * 8192 * 1024) + off;
  } else {
    int off = i - 3 * N4X;  // [0, 1024*1024/4)
    src = (const float4*)Wq + off;
    dst = (ushort4*)Wb + off;
  }
  float4 v = *src;
  ushort4 o;
  o.x = f2b(v.x); o.y = f2b(v.y); o.z = f2b(v.z); o.w = f2b(v.w);
  *dst = o;
}

// ---------------------------------------------------------------------------
// Fused QKV linear: C = Xb * Wb^T + bias.  Xb = [3*8192, 1024].
// 1536 blocks; XCD swizzle: 8 bn sharing an A-tile at stride-8 => same XCD
// L2.  V (input 2) stored transposed: Vt[b][e][s].   (R5 mapping verbatim.)
// ---------------------------------------------------------------------------
__global__ __launch_bounds__(256) void gemm_qkv(
    const unsigned short* __restrict__ Xb, const unsigned short* __restrict__ Wb,
    const float* __restrict__ bias, unsigned short* __restrict__ Qb,
    unsigned short* __restrict__ Kb, unsigned short* __restrict__ Vt) {
  __shared__ __align__(16) unsigned short lsA[2][128 * 32];
  __shared__ __align__(16) unsigned short lsB[2][128 * 32];
  const int l = blockIdx.x;
  const int xcd = l & 7, i = l >> 3;
  const int bn = i & 7;
  const int bmg = xcd * 24 + (i >> 3);  // [0,192): global 128-row tile
  const int input = bmg / 64, bm = bmg % 64;
  const unsigned short* A = Xb + (size_t)bmg * 128 * 1024;
  const unsigned short* W = Wb + (size_t)bn * 128 * 1024;

  const int tid = threadIdx.x;
  const int lane = tid & 63, wave = tid >> 6;
  const int m0 = (wave >> 1) * 64, n0 = (wave & 1) * 64;
  const int lrow = lane & 15, g = lane >> 4;

  floatx4 acc[4][4] = {};
  kloop(A, 1024, W, 1024, 32, lsA[0], lsA[1], lsB[0], lsB[1], tid, m0, n0,
        lrow, g, acc);

  unsigned short* C = (input == 0) ? Qb : (input == 1) ? Kb : Vt;
  const int rb = (lane >> 4) * 4;  // C/D: col=lane&15, row=(lane>>4)*4+reg
#pragma unroll
  for (int mi = 0; mi < 4; ++mi)
#pragma unroll
    for (int ni = 0; ni < 4; ++ni) {
      int gcol = bn * 128 + n0 + ni * 16 + lrow;
      float bv = bias[gcol];
#pragma unroll
      for (int r = 0; r < 4; ++r) {
        int grow = bm * 128 + m0 + mi * 16 + rb + r;
        unsigned short val = f2b(acc[mi][ni][r] + bv);
        if (input == 2) {
          int b = grow >> 11, s = grow & 2047;
          C[((size_t)b * 1024 + gcol) * 2048 + s] = val;
        } else {
          C[(size_t)grow * 1024 + gcol] = val;
        }
      }
    }
}

// ---------------------------------------------------------------------------
// Scores+exp: P[z][q,k] = exp(Q.K/32) (unnorm, bf16; 0 where k>q), and
// l[z*2048+q] += row sums (atomic).  Lower-tri 128-blocks only; swizzle: 768
// ids, 2 XCDs/batch, groups of 8 bn share a Q tile per XCD.  (R5 verbatim.)
// ---------------------------------------------------------------------------
__global__ __launch_bounds__(256) void gemm_scores_exp(
    const unsigned short* __restrict__ Qb,
    const unsigned short* __restrict__ Kb, unsigned short* __restrict__ P,
    float* __restrict__ lsum) {
  const int l = blockIdx.x;
  const int xcd = l & 7, k = l >> 3;
  const int m = k & 7, gl = k >> 3;
  const int gg = xcd * 12 + gl;
  const int z = gg / 24, r0 = gg % 24;
  const int bm = (r0 < 8) ? r0 : 8 + ((r0 - 8) >> 1);
  const int bn = ((r0 < 8) ? 0 : ((r0 - 8) & 1)) * 8 + m;
  if (bn > bm) return;

  __shared__ __align__(16) unsigned short lsA[2][128 * 32];
  __shared__ __align__(16) unsigned short lsB[2][128 * 32];
  const unsigned short* A = Qb + ((size_t)z * S_ + bm * 128) * E_;
  const unsigned short* Bt = Kb + ((size_t)z * S_ + bn * 128) * E_;
  const int tid = threadIdx.x;
  const int lane = tid & 63, wave = tid >> 6;
  const int m0 = (wave >> 1) * 64, n0 = (wave & 1) * 64;
  const int lrow = lane & 15, g = lane >> 4;

  floatx4 acc[4][4] = {};
  kloop(A, E_, Bt, E_, 32, lsA[0], lsA[1], lsB[0], lsB[1], tid, m0, n0, lrow,
        g, acc);

  const int rb = (lane >> 4) * 4;
  const bool diag = (bm == bn);
#pragma unroll
  for (int mi = 0; mi < 4; ++mi)
#pragma unroll
    for (int r = 0; r < 4; ++r) {
      const int grow = bm * 128 + m0 + mi * 16 + rb + r;
      float rsum = 0.f;
#pragma unroll
      for (int ni = 0; ni < 4; ++ni) {
        const int gcol = bn * 128 + n0 + ni * 16 + lrow;
        float p = __expf(acc[mi][ni][r] * 0.03125f);
        if (diag && gcol > grow) p = 0.f;
        P[((size_t)z * S_ + grow) * S_ + gcol] = f2b(p);
        rsum += p;
      }
      // reduce over the 16 lanes holding this row's 64 columns
#pragma unroll
      for (int off = 1; off < 16; off <<= 1) rsum += __shfl_xor(rsum, off);
      if ((lane & 15) == 0) atomicAdd(&lsum[z * S_ + grow], rsum);
    }
}

// ---------------------------------------------------------------------------
// PV: out[z][q,e] = (P V) / l[q], K truncated at (bm+1)*128.
// 512 blocks, pair-balanced: xcd handles bm in {15-xcd, xcd} for all 4 z;
// 8 bn per row-tile share the P tile on one XCD.  (R5 mapping verbatim.)
// ---------------------------------------------------------------------------
__global__ __launch_bounds__(256) void gemm_pv(
    const unsigned short* __restrict__ Pb,
    const unsigned short* __restrict__ Vt, const float* __restrict__ lsum,
    float* __restrict__ Out) {
  __shared__ __align__(16) unsigned short lsA[2][128 * 32];
  __shared__ __align__(16) unsigned short lsB[2][128 * 32];
  const int l = blockIdx.x;
  const int xcd = l & 7, i = l >> 3;
  const int bn = i & 7, j = i >> 3;
  const int z = j >> 1;
  const int bm = (j & 1) ? xcd : 15 - xcd;

  const unsigned short* A = Pb + ((size_t)z * S_ + bm * 128) * S_;
  const unsigned short* Bt = Vt + ((size_t)z * E_ + bn * 128) * S_;
  float* C = Out + (size_t)z * S_ * E_;
  const int tid = threadIdx.x;
  const int lane = tid & 63, wave = tid >> 6;
  const int m0 = (wave >> 1) * 64, n0 = (wave & 1) * 64;
  const int lrow = lane & 15, g = lane >> 4;

  floatx4 acc[4][4] = {};
  const int NT = (bm + 1) * 4;  // BK=32 tiles, covers k <= bm*128+127
  kloop(A, S_, Bt, S_, NT, lsA[0], lsA[1], lsB[0], lsB[1], tid, m0, n0, lrow,
        g, acc);

  const int rb = (lane >> 4) * 4;
#pragma unroll
  for (int mi = 0; mi < 4; ++mi)
#pragma unroll
    for (int r = 0; r < 4; ++r) {
      const int grow = bm * 128 + m0 + mi * 16 + rb + r;
      const float inv = 1.0f / lsum[z * S_ + grow];
#pragma unroll
      for (int ni = 0; ni < 4; ++ni) {
        const int gcol = bn * 128 + n0 + ni * 16 + lrow;
        C[(size_t)grow * E_ + gcol] = acc[mi][ni][r] * inv;
      }
    }
}

// ---------------------------------------------------------------------------
extern "C" void kernel_launch(void* const* d_in, const int* in_sizes, int n_in,
                              void* d_out, int out_size, void* d_ws,
                              size_t ws_size, hipStream_t stream) {
  (void)in_sizes; (void)n_in; (void)out_size; (void)ws_size;
  const float* xq = (const float*)d_in[0];
  const float* xk = (const float*)d_in[1];
  const float* xv = (const float*)d_in[2];
  const float* Wq = (const float*)d_in[3];
  const float* bq = (const float*)d_in[4];
  // d_in[5] att_mask: exact triu(k=1) causal mask, handled analytically.
  float* out = (float*)d_out;

  // workspace (<= 114 MB used):
  //  [0,48M):  Xb (bf16 3*8192*1024) during cvt+QKV; then reused as
  //            P (bf16 4*2048*2048 = 32M) by scores/pv.
  //  [48,50M): Wb  [50,66M): Qb  [66,82M): Kb  [82,98M): Vt
  //  [98M, 98M+32K): l (fp32 row sums)
  unsigned short* base16 = (unsigned short*)d_ws;
  unsigned short* Xb = base16;
  unsigned short* P = base16;
  unsigned short* Wb = base16 + (size_t)24 * 1024 * 1024;  // +48MB
  unsigned short* Qb = Wb + (size_t)1024 * 1024;
  unsigned short* Kb = Qb + (size_t)8192 * 1024;
  unsigned short* Vt = Kb + (size_t)8192 * 1024;
  float* lsum = (float*)(Vt + (size_t)8192 * 1024);  // +98MB, 32KB

  hipMemsetAsync(lsum, 0, BATCH * S_ * sizeof(float), stream);

  const int n4tot = 3 * N4X + 1024 * 1024 / 4;
  cvt_all<<<n4tot / 256, 256, 0, stream>>>(xq, xk, xv, Wq, Xb, Wb);

  gemm_qkv<<<1536, 256, 0, stream>>>(Xb, Wb, bq, Qb, Kb, Vt);
  gemm_scores_exp<<<768, 256, 0, stream>>>(Qb, Kb, P, lsum);
  gemm_pv<<<512, 256, 0, stream>>>(P, Vt, lsum, out);
}